// Round 1
// baseline (1731.189 us; speedup 1.0000x reference)
//
#include <hip/hip_runtime.h>
#include <math.h>

#define NN 100000
#define NE 1600000
#define NG 1024
#define FF 128

// ---------------- histogram ----------------
__global__ void hist_kernel(const int* __restrict__ idx, int* __restrict__ cnt, int n) {
    int i = blockIdx.x * blockDim.x + threadIdx.x;
    if (i < n) atomicAdd(&cnt[idx[i]], 1);
}

// ---------------- scatter edges into CSR ----------------
__global__ void scatter_kernel(const int* __restrict__ src, const int* __restrict__ dst,
                               int* __restrict__ cursor, int* __restrict__ ssrc, int n) {
    int i = blockIdx.x * blockDim.x + threadIdx.x;
    if (i < n) {
        int p = atomicAdd(&cursor[dst[i]], 1);
        ssrc[p] = src[i];
    }
}

// ---------------- exclusive scan of histogram (single block) ----------------
__global__ __launch_bounds__(1024)
void scan_hist(const int* __restrict__ in, int* __restrict__ off_out,
               int* __restrict__ cur_out, float* __restrict__ inv_out, int n) {
    __shared__ int wsum[16];
    __shared__ int carry_s;
    const int t = threadIdx.x, lane = t & 63, wid = t >> 6;
    if (t == 0) carry_s = 0;
    __syncthreads();
    for (int base = 0; base < n; base += 1024) {
        int i = base + t;
        int v = (i < n) ? in[i] : 0;
        int x = v;
        #pragma unroll
        for (int o = 1; o < 64; o <<= 1) {
            int y = __shfl_up(x, o);
            if (lane >= o) x += y;
        }
        if (lane == 63) wsum[wid] = x;
        __syncthreads();
        if (t == 0) {
            int s = carry_s;
            #pragma unroll
            for (int w2 = 0; w2 < 16; ++w2) { int tv = wsum[w2]; wsum[w2] = s; s += tv; }
            carry_s = s;
        }
        __syncthreads();
        int excl = wsum[wid] + x - v;
        if (i < n) {
            off_out[i] = excl;
            if (cur_out) cur_out[i] = excl;
            if (inv_out) inv_out[i] = 1.0f / (float)(v > 1 ? v : 1);
        }
        __syncthreads();
    }
    if (t == 0) off_out[n] = carry_s;
}

// ---------------- SAGE mean aggregation: wave (block of 64) per node ----------------
__global__ __launch_bounds__(64)
void sage_agg(const float* __restrict__ h, const int* __restrict__ row_off,
              const int* __restrict__ ssrc, const float* __restrict__ inv_deg,
              float* __restrict__ out) {
    const int node = blockIdx.x;
    const int lane = threadIdx.x;
    const int beg = row_off[node], end = row_off[node + 1];
    const int j = lane * 2;
    float ax = 0.f, ay = 0.f;
    for (int e = beg; e < end; ++e) {
        int s = ssrc[e];
        float2 v = *(const float2*)&h[(size_t)s * FF + j];
        ax += v.x; ay += v.y;
    }
    float id = inv_deg[node];
    float2 o = {ax * id, ay * id};
    *(float2*)&out[(size_t)node * FF + j] = o;
}

// ---------------- mean pool per graph ----------------
__global__ __launch_bounds__(128)
void pool_mean(const float* __restrict__ src, const int* __restrict__ g_off,
               const float* __restrict__ inv_cnt, float* __restrict__ out) {
    const int g = blockIdx.x;
    const int j = threadIdx.x;
    const int beg = g_off[g], end = g_off[g + 1];
    float s = 0.f;
    for (int n = beg; n < end; ++n) s += src[(size_t)n * FF + j];
    out[(size_t)g * FF + j] = s * inv_cnt[g];
}

// ---------------- D = h - gm[batch] ----------------
__global__ __launch_bounds__(256)
void mdf_diff(const float* __restrict__ h, const float* __restrict__ gm,
              const int* __restrict__ batch, float* __restrict__ D) {
    int i4 = blockIdx.x * blockDim.x + threadIdx.x;   // float4 index, N*32 total
    int node = i4 >> 5, c4 = i4 & 31;
    if (node >= NN) return;
    int g = batch[node];
    float4 hv = *(const float4*)&h[(size_t)node * FF + c4 * 4];
    float4 gv = *(const float4*)&gm[(size_t)g * FF + c4 * 4];
    float4 d = {hv.x - gv.x, hv.y - gv.y, hv.z - gv.z, hv.w - gv.w};
    *(float4*)&D[(size_t)node * FF + c4 * 4] = d;
}

// ---------------- LayerNorm over rows (wave per row) ----------------
__global__ __launch_bounds__(256)
void ln_rows(const float* __restrict__ in, const float* __restrict__ g,
             const float* __restrict__ b, float* __restrict__ out, int M) {
    int w = (blockIdx.x * blockDim.x + threadIdx.x) >> 6;
    int lane = threadIdx.x & 63;
    if (w >= M) return;
    float2 v = *(const float2*)&in[(size_t)w * FF + lane * 2];
    float s1 = v.x + v.y, s2 = v.x * v.x + v.y * v.y;
    #pragma unroll
    for (int o = 32; o >= 1; o >>= 1) { s1 += __shfl_xor(s1, o); s2 += __shfl_xor(s2, o); }
    float mu = s1 * (1.f / FF);
    float rs = rsqrtf(s2 * (1.f / FF) - mu * mu + 1e-5f);
    float2 o2 = {(v.x - mu) * rs * g[lane * 2] + b[lane * 2],
                 (v.y - mu) * rs * g[lane * 2 + 1] + b[lane * 2 + 1]};
    *(float2*)&out[(size_t)w * FF + lane * 2] = o2;
}

// ---------------- tiled GEMM: out[M x 128] = A[M x 128] @ W[128 x 128] (+A2@W2)(+bias)
//                  (+rvec*rrow rank1)(+res)(elu)(LN)  — grid.x * 32 == M exactly
template<bool DUAL, bool R1, bool RES, int ACT, bool LN>
__global__ __launch_bounds__(256)
void gemm128(const float* __restrict__ A, const float* __restrict__ A2,
             const float* __restrict__ W, const float* __restrict__ W2,
             const float* __restrict__ bias,
             const float* __restrict__ rvec, const float* __restrict__ rrow,
             const float* __restrict__ res,
             const float* __restrict__ lng, const float* __restrict__ lnb,
             float* __restrict__ out) {
    __shared__ float Wt[32][128];
    __shared__ float At[32][36];
    __shared__ float W2t[DUAL ? 32 : 1][DUAL ? 128 : 1];
    __shared__ float A2t[DUAL ? 32 : 1][DUAL ? 36 : 1];

    const int t = threadIdx.x;
    const int tx = t & 31, ty = t >> 5;
    const int m0 = blockIdx.x * 32;
    const int lr = t >> 3;   // node row for A staging
    const int lc = t & 7;    // k-float4 for A staging
    float acc[4][4] = {};

    for (int kk = 0; kk < 128; kk += 32) {
        __syncthreads();
        #pragma unroll
        for (int p2 = 0; p2 < 4; ++p2) {
            int q = t + p2 * 256;
            int r = q >> 5, c = q & 31;
            *(float4*)&Wt[r][c * 4] = *(const float4*)&W[(size_t)(kk + r) * 128 + c * 4];
        }
        if (DUAL) {
            #pragma unroll
            for (int p2 = 0; p2 < 4; ++p2) {
                int q = t + p2 * 256;
                int r = q >> 5, c = q & 31;
                *(float4*)&W2t[r][c * 4] = *(const float4*)&W2[(size_t)(kk + r) * 128 + c * 4];
            }
        }
        {
            float4 av = *(const float4*)&A[(size_t)(m0 + lr) * 128 + kk + lc * 4];
            At[lc * 4 + 0][lr] = av.x; At[lc * 4 + 1][lr] = av.y;
            At[lc * 4 + 2][lr] = av.z; At[lc * 4 + 3][lr] = av.w;
            if (DUAL) {
                float4 a2 = *(const float4*)&A2[(size_t)(m0 + lr) * 128 + kk + lc * 4];
                A2t[lc * 4 + 0][lr] = a2.x; A2t[lc * 4 + 1][lr] = a2.y;
                A2t[lc * 4 + 2][lr] = a2.z; A2t[lc * 4 + 3][lr] = a2.w;
            }
        }
        __syncthreads();
        #pragma unroll
        for (int k = 0; k < 32; ++k) {
            float4 a = *(const float4*)&At[k][ty * 4];
            float4 wv = *(const float4*)&Wt[k][tx * 4];
            float am[4] = {a.x, a.y, a.z, a.w};
            float wm[4] = {wv.x, wv.y, wv.z, wv.w};
            #pragma unroll
            for (int mi = 0; mi < 4; ++mi)
                #pragma unroll
                for (int ci = 0; ci < 4; ++ci)
                    acc[mi][ci] += am[mi] * wm[ci];
            if (DUAL) {
                float4 a2 = *(const float4*)&A2t[k][ty * 4];
                float4 w2 = *(const float4*)&W2t[k][tx * 4];
                float am2[4] = {a2.x, a2.y, a2.z, a2.w};
                float wm2[4] = {w2.x, w2.y, w2.z, w2.w};
                #pragma unroll
                for (int mi = 0; mi < 4; ++mi)
                    #pragma unroll
                    for (int ci = 0; ci < 4; ++ci)
                        acc[mi][ci] += am2[mi] * wm2[ci];
            }
        }
    }

    const int j0 = tx * 4;
    float4 bv = *(const float4*)&bias[j0];
    float rr0[4];
    if (R1) { float4 rv = *(const float4*)&rrow[j0]; rr0[0] = rv.x; rr0[1] = rv.y; rr0[2] = rv.z; rr0[3] = rv.w; }
    float gv4[4], bb4[4];
    if (LN) {
        float4 gg = *(const float4*)&lng[j0];
        float4 bb = *(const float4*)&lnb[j0];
        gv4[0] = gg.x; gv4[1] = gg.y; gv4[2] = gg.z; gv4[3] = gg.w;
        bb4[0] = bb.x; bb4[1] = bb.y; bb4[2] = bb.z; bb4[3] = bb.w;
    }

    #pragma unroll
    for (int mi = 0; mi < 4; ++mi) {
        const int m = m0 + ty * 4 + mi;
        float v[4] = {acc[mi][0] + bv.x, acc[mi][1] + bv.y,
                      acc[mi][2] + bv.z, acc[mi][3] + bv.w};
        if (R1) {
            float wv_ = rvec[m];
            #pragma unroll
            for (int ci = 0; ci < 4; ++ci) v[ci] += wv_ * rr0[ci];
        }
        if (RES) {
            float4 rsv = *(const float4*)&res[(size_t)m * 128 + j0];
            v[0] += rsv.x; v[1] += rsv.y; v[2] += rsv.z; v[3] += rsv.w;
        }
        if (ACT == 1) {
            #pragma unroll
            for (int ci = 0; ci < 4; ++ci) v[ci] = v[ci] > 0.f ? v[ci] : expm1f(v[ci]);
        }
        if (LN) {
            float s1 = v[0] + v[1] + v[2] + v[3];
            float s2 = v[0] * v[0] + v[1] * v[1] + v[2] * v[2] + v[3] * v[3];
            #pragma unroll
            for (int o = 16; o >= 1; o >>= 1) { s1 += __shfl_xor(s1, o); s2 += __shfl_xor(s2, o); }
            float mu = s1 * (1.f / 128.f);
            float rs = rsqrtf(s2 * (1.f / 128.f) - mu * mu + 1e-5f);
            #pragma unroll
            for (int ci = 0; ci < 4; ++ci) v[ci] = (v[ci] - mu) * rs * gv4[ci] + bb4[ci];
        }
        float4 ov = {v[0], v[1], v[2], v[3]};
        *(float4*)&out[(size_t)m * 128 + j0] = ov;
    }
}

extern "C" void kernel_launch(void* const* d_in, const int* in_sizes, int n_in,
                              void* d_out, int out_size, void* d_ws, size_t ws_size,
                              hipStream_t stream) {
    const float* x      = (const float*)d_in[0];
    const float* w      = (const float*)d_in[1];
    const int*   ei     = (const int*)d_in[2];
    const int*   batch  = (const int*)d_in[3];
    const float* W_in   = (const float*)d_in[4];
    const float* b_in   = (const float*)d_in[5];
    const float* sage_Wl = (const float*)d_in[6];
    const float* sage_bl = (const float*)d_in[7];
    const float* sage_Wr = (const float*)d_in[8];
    const float* ln1_g  = (const float*)d_in[9];
    const float* ln1_b  = (const float*)d_in[10];
    const float* lin1_W = (const float*)d_in[11];
    const float* lin1_b = (const float*)d_in[12];
    const float* lin2_W = (const float*)d_in[13];
    const float* lin2_b = (const float*)d_in[14];
    const float* ln2_g  = (const float*)d_in[15];
    const float* ln2_b  = (const float*)d_in[16];
    const float* mdf_W  = (const float*)d_in[17];
    const float* mdf_b  = (const float*)d_in[18];
    const float* pln1_g = (const float*)d_in[19];
    const float* pln1_b = (const float*)d_in[20];
    const float* plin1_W = (const float*)d_in[21];
    const float* plin1_b = (const float*)d_in[22];
    const float* plin2_W = (const float*)d_in[23];
    const float* plin2_b = (const float*)d_in[24];
    const float* pln2_g = (const float*)d_in[25];
    const float* pln2_b = (const float*)d_in[26];
    float* out = (float*)d_out;

    const int* e_src = ei;
    const int* e_dst = ei + NE;

    // ---- workspace layout (floats first, all 16B aligned) ----
    float* ws = (float*)d_ws;
    size_t off = 0;
    float* h     = ws + off; off += (size_t)NN * FF;
    float* bufa  = ws + off; off += (size_t)NN * FF;
    float* bufb  = ws + off; off += (size_t)NN * FF;
    float* gm    = ws + off; off += (size_t)NG * FF;
    float* pp    = ws + off; off += (size_t)NG * FF;
    float* hh    = ws + off; off += (size_t)NG * FF;
    float* tt    = ws + off; off += (size_t)NG * FF;
    float* inv_deg = ws + off; off += NN;
    float* inv_cnt = ws + off; off += NG;
    int* iw = (int*)(ws + off);
    size_t ioff = 0;
    int* deg_i   = iw + ioff; ioff += NN;
    int* row_off = iw + ioff; ioff += NN + 1;
    int* cursor  = iw + ioff; ioff += NN + 1;
    int* cnt_i   = iw + ioff; ioff += NG;
    int* g_off   = iw + ioff; ioff += NG + 1;
    int* ssrc    = iw + ioff; ioff += NE;

    // ---- build CSR + graph offsets ----
    hipMemsetAsync(deg_i, 0, sizeof(int) * NN, stream);
    hipMemsetAsync(cnt_i, 0, sizeof(int) * NG, stream);
    hist_kernel<<<(NE + 255) / 256, 256, 0, stream>>>(e_dst, deg_i, NE);
    hist_kernel<<<(NN + 255) / 256, 256, 0, stream>>>(batch, cnt_i, NN);
    scan_hist<<<1, 1024, 0, stream>>>(deg_i, row_off, cursor, inv_deg, NN);
    scan_hist<<<1, 1024, 0, stream>>>(cnt_i, g_off, (int*)nullptr, inv_cnt, NG);
    scatter_kernel<<<(NE + 255) / 256, 256, 0, stream>>>(e_src, e_dst, cursor, ssrc, NE);

    const int GN = NN / 32;   // 3125 blocks, exact
    const int GB = NG / 32;   // 32 blocks, exact

    // ---- input linear: h = [x | w] @ W_in + b_in ----
    gemm128<false, true, false, 0, false><<<GN, 256, 0, stream>>>(
        x, nullptr, W_in, nullptr, b_in, w, W_in + 128 * 128, nullptr, nullptr, nullptr, h);

    // ---- 3 GC blocks ----
    for (int l = 0; l < 3; ++l) {
        const float* Wl = sage_Wl + (size_t)l * FF * FF;
        const float* bl = sage_bl + (size_t)l * FF;
        const float* Wr = sage_Wr + (size_t)l * FF * FF;
        const float* g1 = ln1_g + (size_t)l * FF;
        const float* b1 = ln1_b + (size_t)l * FF;
        const float* W1 = lin1_W + (size_t)l * FF * FF;
        const float* bb1 = lin1_b + (size_t)l * FF;
        const float* W2 = lin2_W + (size_t)l * FF * FF;
        const float* bb2 = lin2_b + (size_t)l * FF;
        const float* g2 = ln2_g + (size_t)l * FF;
        const float* b2 = ln2_b + (size_t)l * FF;

        sage_agg<<<NN, 64, 0, stream>>>(h, row_off, ssrc, inv_deg, bufa);
        // y1 = LN(agg@Wl + h@Wr + h + bl)
        gemm128<true, false, true, 0, true><<<GN, 256, 0, stream>>>(
            bufa, h, Wl, Wr, bl, nullptr, nullptr, h, g1, b1, bufb);
        // t = elu(y1@W1 + bb1)
        gemm128<false, false, false, 1, false><<<GN, 256, 0, stream>>>(
            bufb, nullptr, W1, nullptr, bb1, nullptr, nullptr, nullptr, nullptr, nullptr, bufa);
        // h = LN(t@W2 + bb2 + y1)
        gemm128<false, false, true, 0, true><<<GN, 256, 0, stream>>>(
            bufa, nullptr, W2, nullptr, bb2, nullptr, nullptr, bufb, g2, b2, h);
    }

    // ---- MeanDiffFeatureBlock ----
    pool_mean<<<NG, 128, 0, stream>>>(h, g_off, inv_cnt, gm);
    mdf_diff<<<(NN * 32 + 255) / 256, 256, 0, stream>>>(h, gm, batch, bufb);
    // h2 = h@mdf_W[0:128] + D@mdf_W[128:256] + mdf_b
    gemm128<true, false, false, 0, false><<<GN, 256, 0, stream>>>(
        h, bufb, mdf_W, mdf_W + 128 * 128, mdf_b, nullptr, nullptr, nullptr, nullptr, nullptr, bufa);

    // ---- pooled head ----
    pool_mean<<<NG, 128, 0, stream>>>(bufa, g_off, inv_cnt, pp);
    ln_rows<<<(NG * 64 + 255) / 256, 256, 0, stream>>>(pp, pln1_g, pln1_b, hh, NG);
    gemm128<false, false, false, 1, false><<<GB, 256, 0, stream>>>(
        hh, nullptr, plin1_W, nullptr, plin1_b, nullptr, nullptr, nullptr, nullptr, nullptr, tt);
    gemm128<false, false, true, 0, true><<<GB, 256, 0, stream>>>(
        tt, nullptr, plin2_W, nullptr, plin2_b, nullptr, nullptr, hh, pln2_g, pln2_b, out);
}

// Round 2
// 1223.469 us; speedup vs baseline: 1.4150x; 1.4150x over previous
//
#include <hip/hip_runtime.h>
#include <math.h>

#define NN 100000
#define NE 1600000
#define NG 1024
#define FF 128

typedef __attribute__((ext_vector_type(8))) short short8;
typedef __attribute__((ext_vector_type(4))) float f32x4;

__device__ __forceinline__ unsigned short f2b(float f) {
    union { float f; unsigned u; } v; v.f = f;
    unsigned r = (v.u + 0x7FFF + ((v.u >> 16) & 1)) >> 16;
    return (unsigned short)r;
}
__device__ __forceinline__ float b2f_lo(unsigned u) {
    union { unsigned u; float f; } v; v.u = u << 16; return v.f;
}
__device__ __forceinline__ float b2f_hi(unsigned u) {
    union { unsigned u; float f; } v; v.u = u & 0xFFFF0000u; return v.f;
}

// ---------------- histogram ----------------
__global__ void hist_kernel(const int* __restrict__ idx, int* __restrict__ cnt, int n) {
    int i = blockIdx.x * blockDim.x + threadIdx.x;
    if (i < n) atomicAdd(&cnt[idx[i]], 1);
}

// ---------------- scatter edges into CSR ----------------
__global__ void scatter_kernel(const int* __restrict__ src, const int* __restrict__ dst,
                               int* __restrict__ cursor, int* __restrict__ ssrc, int n) {
    int i = blockIdx.x * blockDim.x + threadIdx.x;
    if (i < n) {
        int p = atomicAdd(&cursor[dst[i]], 1);
        ssrc[p] = src[i];
    }
}

// ---------------- exclusive scan of histogram (single block) ----------------
__global__ __launch_bounds__(1024)
void scan_hist(const int* __restrict__ in, int* __restrict__ off_out,
               int* __restrict__ cur_out, float* __restrict__ inv_out, int n) {
    __shared__ int wsum[16];
    __shared__ int carry_s;
    const int t = threadIdx.x, lane = t & 63, wid = t >> 6;
    if (t == 0) carry_s = 0;
    __syncthreads();
    for (int base = 0; base < n; base += 1024) {
        int i = base + t;
        int v = (i < n) ? in[i] : 0;
        int x = v;
        #pragma unroll
        for (int o = 1; o < 64; o <<= 1) {
            int y = __shfl_up(x, o);
            if (lane >= o) x += y;
        }
        if (lane == 63) wsum[wid] = x;
        __syncthreads();
        if (t == 0) {
            int s = carry_s;
            #pragma unroll
            for (int w2 = 0; w2 < 16; ++w2) { int tv = wsum[w2]; wsum[w2] = s; s += tv; }
            carry_s = s;
        }
        __syncthreads();
        int excl = wsum[wid] + x - v;
        if (i < n) {
            off_out[i] = excl;
            if (cur_out) cur_out[i] = excl;
            if (inv_out) inv_out[i] = 1.0f / (float)(v > 1 ? v : 1);
        }
        __syncthreads();
    }
    if (t == 0) off_out[n] = carry_s;
}

// ---------------- weight prep: fp32 [k][n] -> bf16 [n][k] (optionally sum of two) ----
struct WTab { const float* a[17]; const float* b[17]; };
__global__ __launch_bounds__(256)
void prep_weights(WTab tab, unsigned short* __restrict__ dst) {
    int w = blockIdx.x >> 6;
    int idx = ((blockIdx.x & 63) << 8) + threadIdx.x;
    int k = idx >> 7, n = idx & 127;
    float v = tab.a[w][idx];
    if (tab.b[w]) v += tab.b[w][idx];
    dst[(size_t)w * 16384 + n * 128 + k] = f2b(v);
}

// ---------------- SAGE mean aggregation from bf16 h, 4 waves/block ----------------
__global__ __launch_bounds__(256)
void sage_agg(const unsigned short* __restrict__ hb, const int* __restrict__ row_off,
              const int* __restrict__ ssrc, const float* __restrict__ inv_deg,
              unsigned short* __restrict__ aggb) {
    const int wid = threadIdx.x >> 6;
    const int lane = threadIdx.x & 63;
    const int node = blockIdx.x * 4 + wid;
    const int beg = row_off[node], end = row_off[node + 1];
    float ax = 0.f, ay = 0.f;
    int e = beg;
    for (; e + 1 < end; e += 2) {
        int s0 = ssrc[e], s1 = ssrc[e + 1];
        unsigned u0 = *(const unsigned*)&hb[(size_t)s0 * FF + lane * 2];
        unsigned u1 = *(const unsigned*)&hb[(size_t)s1 * FF + lane * 2];
        ax += b2f_lo(u0) + b2f_lo(u1);
        ay += b2f_hi(u0) + b2f_hi(u1);
    }
    if (e < end) {
        int s0 = ssrc[e];
        unsigned u0 = *(const unsigned*)&hb[(size_t)s0 * FF + lane * 2];
        ax += b2f_lo(u0);
        ay += b2f_hi(u0);
    }
    float id = inv_deg[node];
    ushort2 o = {f2b(ax * id), f2b(ay * id)};
    *(ushort2*)&aggb[(size_t)node * FF + lane * 2] = o;
}

// ---------------- mean pool per graph (fp32 in/out) ----------------
__global__ __launch_bounds__(128)
void pool_mean(const float* __restrict__ src, const int* __restrict__ g_off,
               const float* __restrict__ inv_cnt, float* __restrict__ out) {
    const int g = blockIdx.x;
    const int j = threadIdx.x;
    const int beg = g_off[g], end = g_off[g + 1];
    float s = 0.f;
    for (int n = beg; n < end; ++n) s += src[(size_t)n * FF + j];
    out[(size_t)g * FF + j] = s * inv_cnt[g];
}

// ---------------- LayerNorm over rows (wave per row, fp32) ----------------
__global__ __launch_bounds__(256)
void ln_rows(const float* __restrict__ in, const float* __restrict__ g,
             const float* __restrict__ b, float* __restrict__ out, int M) {
    int w = (blockIdx.x * blockDim.x + threadIdx.x) >> 6;
    int lane = threadIdx.x & 63;
    if (w >= M) return;
    float2 v = *(const float2*)&in[(size_t)w * FF + lane * 2];
    float s1 = v.x + v.y, s2 = v.x * v.x + v.y * v.y;
    #pragma unroll
    for (int o = 32; o >= 1; o >>= 1) { s1 += __shfl_xor(s1, o); s2 += __shfl_xor(s2, o); }
    float mu = s1 * (1.f / FF);
    float rs = rsqrtf(s2 * (1.f / FF) - mu * mu + 1e-5f);
    float2 o2 = {(v.x - mu) * rs * g[lane * 2] + b[lane * 2],
                 (v.y - mu) * rs * g[lane * 2 + 1] + b[lane * 2 + 1]};
    *(float2*)&out[(size_t)w * FF + lane * 2] = o2;
}

// ---------------- MFMA bf16 GEMM: out[M x 128] = A @ W (+A2@W2) + epilogue ------
// Block 256 thr (4 waves), M-tile 64 (16 rows/wave), N=128 (8 n-tiles), K=128.
// W given transposed bf16 [n][k]. A either bf16 [m][k] or fp32 (converted).
// RESM: 0 none, 1 v += res[m], 2 v -= res[residx[m]]
template<bool DUAL, bool AB16, bool R1, int RESM, int ACT, bool LN, bool OF32, bool OB16>
__global__ __launch_bounds__(256)
void gemm_mfma(const void* __restrict__ A_, const void* __restrict__ A2_,
               const unsigned short* __restrict__ Wt, const unsigned short* __restrict__ W2t,
               const float* __restrict__ bias,
               const float* __restrict__ rvec, const float* __restrict__ rrow,
               const float* __restrict__ res, const int* __restrict__ residx,
               const float* __restrict__ lng, const float* __restrict__ lnb,
               float* __restrict__ outf, unsigned short* __restrict__ outb, int M) {
    constexpr int NA = DUAL ? 2 : 1;
    __shared__ short Al[NA][64 * 136];     // A tile bf16, stride 136 (2-way bank alias = free)
    __shared__ short Wl[NA][128 * 40];     // W k-chunk bf16 [n][40]

    const int t = threadIdx.x;
    const int lane = t & 63, wid = t >> 6;
    const int m0 = blockIdx.x * 64;

    // ---- stage A tile(s) ----
    if (AB16) {
        const unsigned short* Ab[2] = {(const unsigned short*)A_, (const unsigned short*)A2_};
        #pragma unroll
        for (int s = 0; s < NA; ++s)
            for (int i = t; i < 1024; i += 256) {
                int row = i >> 4, seg = i & 15;
                int gr = m0 + row; if (gr >= M) gr = M - 1;
                uint4 v = *(const uint4*)&Ab[s][(size_t)gr * 128 + seg * 8];
                *(uint4*)&Al[s][row * 136 + seg * 8] = v;
            }
    } else {
        const float* Af[2] = {(const float*)A_, (const float*)A2_};
        #pragma unroll
        for (int s = 0; s < NA; ++s)
            for (int i = t; i < 2048; i += 256) {
                int row = i >> 5, seg = i & 31;
                int gr = m0 + row; if (gr >= M) gr = M - 1;
                float4 v = *(const float4*)&Af[s][(size_t)gr * 128 + seg * 4];
                ushort4 o = {f2b(v.x), f2b(v.y), f2b(v.z), f2b(v.w)};
                *(ushort4*)&Al[s][row * 136 + seg * 4] = o;
            }
    }

    f32x4 acc[8];
    #pragma unroll
    for (int nt = 0; nt < 8; ++nt) acc[nt] = (f32x4){0.f, 0.f, 0.f, 0.f};

    const unsigned short* Wts[2] = {Wt, W2t};
    for (int kc = 0; kc < 4; ++kc) {
        if (kc) __syncthreads();
        #pragma unroll
        for (int s = 0; s < NA; ++s)
            for (int i = t; i < 512; i += 256) {
                int n = i >> 2, seg = i & 3;
                *(uint4*)&Wl[s][n * 40 + seg * 8] =
                    *(const uint4*)&Wts[s][(size_t)n * 128 + kc * 32 + seg * 8];
            }
        __syncthreads();
        const int aoff = (wid * 16 + (lane & 15)) * 136 + kc * 32 + (lane >> 4) * 8;
        short8 a0 = *(const short8*)&Al[0][aoff];
        short8 a1;
        if (DUAL) a1 = *(const short8*)&Al[1][aoff];
        #pragma unroll
        for (int nt = 0; nt < 8; ++nt) {
            const int boff = (nt * 16 + (lane & 15)) * 40 + (lane >> 4) * 8;
            short8 b0 = *(const short8*)&Wl[0][boff];
            acc[nt] = __builtin_amdgcn_mfma_f32_16x16x32_bf16(a0, b0, acc[nt], 0, 0, 0);
            if (DUAL) {
                short8 b1 = *(const short8*)&Wl[1][boff];
                acc[nt] = __builtin_amdgcn_mfma_f32_16x16x32_bf16(a1, b1, acc[nt], 0, 0, 0);
            }
        }
    }

    // ---- epilogue: lane holds rows rq*4+reg, cols nt*16+cb ----
    const int cb = lane & 15, rq = lane >> 4;
    float bs[8], rr[8], lg[8], lb[8];
    #pragma unroll
    for (int nt = 0; nt < 8; ++nt) {
        int col = nt * 16 + cb;
        bs[nt] = bias[col];
        if (R1) rr[nt] = rrow[col];
        if (LN) { lg[nt] = lng[col]; lb[nt] = lnb[col]; }
    }
    #pragma unroll
    for (int reg = 0; reg < 4; ++reg) {
        int m = m0 + wid * 16 + rq * 4 + reg;
        int mc = m < M ? m : M - 1;
        float v[8];
        #pragma unroll
        for (int nt = 0; nt < 8; ++nt) v[nt] = acc[nt][reg] + bs[nt];
        if (R1) {
            float rv = rvec[mc];
            #pragma unroll
            for (int nt = 0; nt < 8; ++nt) v[nt] += rv * rr[nt];
        }
        if (RESM == 1) {
            #pragma unroll
            for (int nt = 0; nt < 8; ++nt) v[nt] += res[(size_t)mc * 128 + nt * 16 + cb];
        }
        if (RESM == 2) {
            int g = residx[mc];
            #pragma unroll
            for (int nt = 0; nt < 8; ++nt) v[nt] -= res[(size_t)g * 128 + nt * 16 + cb];
        }
        if (ACT == 1) {
            #pragma unroll
            for (int nt = 0; nt < 8; ++nt) v[nt] = v[nt] > 0.f ? v[nt] : expm1f(v[nt]);
        }
        if (LN) {
            float s1 = 0.f, s2 = 0.f;
            #pragma unroll
            for (int nt = 0; nt < 8; ++nt) { s1 += v[nt]; s2 += v[nt] * v[nt]; }
            #pragma unroll
            for (int o = 8; o >= 1; o >>= 1) { s1 += __shfl_xor(s1, o); s2 += __shfl_xor(s2, o); }
            float mu = s1 * (1.f / 128.f);
            float rs = rsqrtf(s2 * (1.f / 128.f) - mu * mu + 1e-5f);
            #pragma unroll
            for (int nt = 0; nt < 8; ++nt) v[nt] = (v[nt] - mu) * rs * lg[nt] + lb[nt];
        }
        if (m < M) {
            #pragma unroll
            for (int nt = 0; nt < 8; ++nt) {
                size_t o = (size_t)m * 128 + nt * 16 + cb;
                if (OF32) outf[o] = v[nt];
                if (OB16) outb[o] = f2b(v[nt]);
            }
        }
    }
}

extern "C" void kernel_launch(void* const* d_in, const int* in_sizes, int n_in,
                              void* d_out, int out_size, void* d_ws, size_t ws_size,
                              hipStream_t stream) {
    const float* x      = (const float*)d_in[0];
    const float* w      = (const float*)d_in[1];
    const int*   ei     = (const int*)d_in[2];
    const int*   batch  = (const int*)d_in[3];
    const float* W_in   = (const float*)d_in[4];
    const float* b_in   = (const float*)d_in[5];
    const float* sage_Wl = (const float*)d_in[6];
    const float* sage_bl = (const float*)d_in[7];
    const float* sage_Wr = (const float*)d_in[8];
    const float* ln1_g  = (const float*)d_in[9];
    const float* ln1_b  = (const float*)d_in[10];
    const float* lin1_W = (const float*)d_in[11];
    const float* lin1_b = (const float*)d_in[12];
    const float* lin2_W = (const float*)d_in[13];
    const float* lin2_b = (const float*)d_in[14];
    const float* ln2_g  = (const float*)d_in[15];
    const float* ln2_b  = (const float*)d_in[16];
    const float* mdf_W  = (const float*)d_in[17];
    const float* mdf_b  = (const float*)d_in[18];
    const float* pln1_g = (const float*)d_in[19];
    const float* pln1_b = (const float*)d_in[20];
    const float* plin1_W = (const float*)d_in[21];
    const float* plin1_b = (const float*)d_in[22];
    const float* plin2_W = (const float*)d_in[23];
    const float* plin2_b = (const float*)d_in[24];
    const float* pln2_g = (const float*)d_in[25];
    const float* pln2_b = (const float*)d_in[26];
    float* out = (float*)d_out;

    const int* e_src = ei;
    const int* e_dst = ei + NE;

    // ---- workspace layout ----
    float* ws = (float*)d_ws;
    size_t off = 0;
    float* h     = ws + off; off += (size_t)NN * FF;
    float* bufb  = ws + off; off += (size_t)NN * FF;   // y1 fp32
    float* gm    = ws + off; off += (size_t)NG * FF;
    float* gm2   = ws + off; off += (size_t)NG * FF;
    float* pp    = ws + off; off += (size_t)NG * FF;
    float* hh    = ws + off; off += (size_t)NG * FF;
    float* tt    = ws + off; off += (size_t)NG * FF;
    float* inv_deg = ws + off; off += NN;
    float* inv_cnt = ws + off; off += NG;
    float* zb      = ws + off; off += FF;
    unsigned short* us = (unsigned short*)(ws + off);
    size_t uoff = 0;
    unsigned short* hb   = us + uoff; uoff += (size_t)NN * FF;
    unsigned short* aggb = us + uoff; uoff += (size_t)NN * FF;  // also reused as tb
    unsigned short* y1b  = us + uoff; uoff += (size_t)NN * FF;
    unsigned short* wt   = us + uoff; uoff += (size_t)17 * 16384;
    int* iw = (int*)(us + uoff);
    size_t ioff = 0;
    int* deg_i   = iw + ioff; ioff += NN;
    int* row_off = iw + ioff; ioff += NN + 1;
    int* cursor  = iw + ioff; ioff += NN + 1;
    int* cnt_i   = iw + ioff; ioff += NG;
    int* g_off   = iw + ioff; ioff += NG + 1;
    int* ssrc    = iw + ioff; ioff += NE;

    // ---- weight prep ----
    WTab tab;
    for (int i = 0; i < 17; ++i) { tab.a[i] = nullptr; tab.b[i] = nullptr; }
    tab.a[0] = W_in;
    for (int l = 0; l < 3; ++l) {
        tab.a[1 + l]  = sage_Wl + (size_t)l * 16384;
        tab.a[4 + l]  = sage_Wr + (size_t)l * 16384;
        tab.a[7 + l]  = lin1_W + (size_t)l * 16384;
        tab.a[10 + l] = lin2_W + (size_t)l * 16384;
    }
    tab.a[13] = mdf_W; tab.b[13] = mdf_W + 16384;   // Wsum = Wa + Wb
    tab.a[14] = mdf_W + 16384;                       // Wb
    tab.a[15] = plin1_W;
    tab.a[16] = plin2_W;
    prep_weights<<<17 * 64, 256, 0, stream>>>(tab, wt);
    const unsigned short* win_t  = wt + 0 * 16384;
    const unsigned short* wsum_t = wt + 13 * 16384;
    const unsigned short* wb_t   = wt + 14 * 16384;
    const unsigned short* p1_t   = wt + 15 * 16384;
    const unsigned short* p2_t   = wt + 16 * 16384;

    // ---- build CSR + graph offsets ----
    hipMemsetAsync(deg_i, 0, sizeof(int) * NN, stream);
    hipMemsetAsync(cnt_i, 0, sizeof(int) * NG, stream);
    hipMemsetAsync(zb, 0, sizeof(float) * FF, stream);
    hist_kernel<<<(NE + 255) / 256, 256, 0, stream>>>(e_dst, deg_i, NE);
    hist_kernel<<<(NN + 255) / 256, 256, 0, stream>>>(batch, cnt_i, NN);
    scan_hist<<<1, 1024, 0, stream>>>(deg_i, row_off, cursor, inv_deg, NN);
    scan_hist<<<1, 1024, 0, stream>>>(cnt_i, g_off, (int*)nullptr, inv_cnt, NG);
    scatter_kernel<<<(NE + 255) / 256, 256, 0, stream>>>(e_src, e_dst, cursor, ssrc, NE);

    const int GN = (NN + 63) / 64;   // 1563
    const int GB = NG / 64;          // 16

    // ---- input linear: h = x @ W_in[0:128] + w * W_in[128] + b_in ----
    gemm_mfma<false, false, true, 0, 0, false, true, true><<<GN, 256, 0, stream>>>(
        x, nullptr, win_t, nullptr, b_in, w, W_in + 128 * 128,
        nullptr, nullptr, nullptr, nullptr, h, hb, NN);

    // ---- 3 GC blocks ----
    for (int l = 0; l < 3; ++l) {
        const unsigned short* Wl_t = wt + (size_t)(1 + l) * 16384;
        const unsigned short* Wr_t = wt + (size_t)(4 + l) * 16384;
        const unsigned short* W1_t = wt + (size_t)(7 + l) * 16384;
        const unsigned short* W2_t = wt + (size_t)(10 + l) * 16384;
        const float* bl  = sage_bl + (size_t)l * FF;
        const float* g1  = ln1_g + (size_t)l * FF;
        const float* b1  = ln1_b + (size_t)l * FF;
        const float* bb1 = lin1_b + (size_t)l * FF;
        const float* bb2 = lin2_b + (size_t)l * FF;
        const float* g2  = ln2_g + (size_t)l * FF;
        const float* b2  = ln2_b + (size_t)l * FF;

        sage_agg<<<NN / 4, 256, 0, stream>>>(hb, row_off, ssrc, inv_deg, aggb);
        // y1 = LN(agg@Wl + h@Wr + h + bl) -> bufb (f32) + y1b (bf16)
        gemm_mfma<true, true, false, 1, 0, true, true, true><<<GN, 256, 0, stream>>>(
            aggb, hb, Wl_t, Wr_t, bl, nullptr, nullptr, h, nullptr, g1, b1, bufb, y1b, NN);
        // t = elu(y1@W1 + bb1) -> tb (bf16 only, aliases aggb)
        gemm_mfma<false, true, false, 0, 1, false, false, true><<<GN, 256, 0, stream>>>(
            y1b, nullptr, W1_t, nullptr, bb1, nullptr, nullptr,
            nullptr, nullptr, nullptr, nullptr, nullptr, aggb, NN);
        // h = LN(t@W2 + bb2 + y1) -> h (f32) + hb (bf16)
        gemm_mfma<false, true, false, 1, 0, true, true, true><<<GN, 256, 0, stream>>>(
            aggb, nullptr, W2_t, nullptr, bb2, nullptr, nullptr, bufb, nullptr, g2, b2, h, hb, NN);
    }

    // ---- MeanDiffFeatureBlock: h2 = h@(Wa+Wb) - gm[batch]@Wb + mdf_b ----
    pool_mean<<<NG, 128, 0, stream>>>(h, g_off, inv_cnt, gm);
    gemm_mfma<false, false, false, 0, 0, false, true, false><<<GB, 256, 0, stream>>>(
        gm, nullptr, wb_t, nullptr, zb, nullptr, nullptr,
        nullptr, nullptr, nullptr, nullptr, gm2, nullptr, NG);
    gemm_mfma<false, true, false, 2, 0, false, true, false><<<GN, 256, 0, stream>>>(
        hb, nullptr, wsum_t, nullptr, mdf_b, nullptr, nullptr,
        gm2, batch, nullptr, nullptr, h, nullptr, NN);

    // ---- pooled head ----
    pool_mean<<<NG, 128, 0, stream>>>(h, g_off, inv_cnt, pp);
    ln_rows<<<(NG * 64 + 255) / 256, 256, 0, stream>>>(pp, pln1_g, pln1_b, hh, NG);
    gemm_mfma<false, false, false, 0, 1, false, true, false><<<GB, 256, 0, stream>>>(
        hh, nullptr, p1_t, nullptr, plin1_b, nullptr, nullptr,
        nullptr, nullptr, nullptr, nullptr, tt, nullptr, NG);
    gemm_mfma<false, false, false, 1, 0, true, true, false><<<GB, 256, 0, stream>>>(
        tt, nullptr, p2_t, nullptr, plin2_b, nullptr, nullptr,
        hh, nullptr, pln2_g, pln2_b, out, nullptr, NG);
}

// Round 3
// 978.301 us; speedup vs baseline: 1.7696x; 1.2506x over previous
//
#include <hip/hip_runtime.h>
#include <math.h>

#define NN 100000
#define NE 1600000
#define NG 1024
#define FF 128

typedef __attribute__((ext_vector_type(8))) short short8;
typedef __attribute__((ext_vector_type(4))) float f32x4;

__device__ __forceinline__ unsigned short f2b(float f) {
    union { float f; unsigned u; } v; v.f = f;
    unsigned r = (v.u + 0x7FFF + ((v.u >> 16) & 1)) >> 16;
    return (unsigned short)r;
}
__device__ __forceinline__ float us2f(unsigned short u) {
    union { unsigned u; float f; } v; v.u = ((unsigned)u) << 16; return v.f;
}
__device__ __forceinline__ float b2f_lo(unsigned u) {
    union { unsigned u; float f; } v; v.u = u << 16; return v.f;
}
__device__ __forceinline__ float b2f_hi(unsigned u) {
    union { unsigned u; float f; } v; v.u = u & 0xFFFF0000u; return v.f;
}

// ---------------- histogram ----------------
__global__ void hist_kernel(const int* __restrict__ idx, int* __restrict__ cnt, int n) {
    int i = blockIdx.x * blockDim.x + threadIdx.x;
    if (i < n) atomicAdd(&cnt[idx[i]], 1);
}

// ---------------- scatter edges into CSR ----------------
__global__ void scatter_kernel(const int* __restrict__ src, const int* __restrict__ dst,
                               int* __restrict__ cursor, int* __restrict__ ssrc, int n) {
    int i = blockIdx.x * blockDim.x + threadIdx.x;
    if (i < n) {
        int p = atomicAdd(&cursor[dst[i]], 1);
        ssrc[p] = src[i];
    }
}

// ---------------- exclusive scan of histogram (single block) ----------------
__global__ __launch_bounds__(1024)
void scan_hist(const int* __restrict__ in, int* __restrict__ off_out,
               int* __restrict__ cur_out, float* __restrict__ inv_out, int n) {
    __shared__ int wsum[16];
    __shared__ int carry_s;
    const int t = threadIdx.x, lane = t & 63, wid = t >> 6;
    if (t == 0) carry_s = 0;
    __syncthreads();
    for (int base = 0; base < n; base += 1024) {
        int i = base + t;
        int v = (i < n) ? in[i] : 0;
        int x = v;
        #pragma unroll
        for (int o = 1; o < 64; o <<= 1) {
            int y = __shfl_up(x, o);
            if (lane >= o) x += y;
        }
        if (lane == 63) wsum[wid] = x;
        __syncthreads();
        if (t == 0) {
            int s = carry_s;
            #pragma unroll
            for (int w2 = 0; w2 < 16; ++w2) { int tv = wsum[w2]; wsum[w2] = s; s += tv; }
            carry_s = s;
        }
        __syncthreads();
        int excl = wsum[wid] + x - v;
        if (i < n) {
            off_out[i] = excl;
            if (cur_out) cur_out[i] = excl;
            if (inv_out) inv_out[i] = 1.0f / (float)(v > 1 ? v : 1);
        }
        __syncthreads();
    }
    if (t == 0) off_out[n] = carry_s;
}

// ---------------- weight prep: fp32 [k][n] -> bf16 [n][k] ----------------
struct WTab { const float* a[16]; };
__global__ __launch_bounds__(256)
void prep_weights(WTab tab, unsigned short* __restrict__ dst) {
    int w = blockIdx.x >> 6;
    int idx = ((blockIdx.x & 63) << 8) + threadIdx.x;
    int k = idx >> 7, n = idx & 127;
    dst[(size_t)w * 16384 + n * 128 + k] = f2b(tab.a[w][idx]);
}

// ---------------- SAGE mean aggregation: 2 edges/wave (32 lanes x 8B) -------
__global__ __launch_bounds__(256)
void sage_agg(const unsigned short* __restrict__ hb, const int* __restrict__ row_off,
              const int* __restrict__ ssrc, const float* __restrict__ inv_deg,
              unsigned short* __restrict__ aggb) {
    const int wid = threadIdx.x >> 6;
    const int lane = threadIdx.x & 63;
    const int node = blockIdx.x * 4 + wid;
    const int half = lane >> 5, j = lane & 31;   // j*4 = col base (4 bf16 per lane)
    const int beg = row_off[node], end = row_off[node + 1];
    float a0 = 0.f, a1 = 0.f, a2 = 0.f, a3 = 0.f;
    int e = beg + half;
    for (; e + 2 < end; e += 4) {
        int s0 = ssrc[e], s1 = ssrc[e + 2];
        uint2 u0 = *(const uint2*)&hb[(size_t)s0 * FF + j * 4];
        uint2 u1 = *(const uint2*)&hb[(size_t)s1 * FF + j * 4];
        a0 += b2f_lo(u0.x) + b2f_lo(u1.x);
        a1 += b2f_hi(u0.x) + b2f_hi(u1.x);
        a2 += b2f_lo(u0.y) + b2f_lo(u1.y);
        a3 += b2f_hi(u0.y) + b2f_hi(u1.y);
    }
    if (e < end) {
        int s0 = ssrc[e];
        uint2 u0 = *(const uint2*)&hb[(size_t)s0 * FF + j * 4];
        a0 += b2f_lo(u0.x); a1 += b2f_hi(u0.x);
        a2 += b2f_lo(u0.y); a3 += b2f_hi(u0.y);
    }
    a0 += __shfl_xor(a0, 32); a1 += __shfl_xor(a1, 32);
    a2 += __shfl_xor(a2, 32); a3 += __shfl_xor(a3, 32);
    if (half == 0) {
        float id = inv_deg[node];
        ushort4 o = {f2b(a0 * id), f2b(a1 * id), f2b(a2 * id), f2b(a3 * id)};
        *(ushort4*)&aggb[(size_t)node * FF + j * 4] = o;
    }
}

// ---------------- mean pool per graph from bf16 ----------------
__global__ __launch_bounds__(128)
void pool_mean_b(const unsigned short* __restrict__ src, const int* __restrict__ g_off,
                 const float* __restrict__ inv_cnt, float* __restrict__ out) {
    const int g = blockIdx.x;
    const int j = threadIdx.x;
    const int beg = g_off[g], end = g_off[g + 1];
    float s = 0.f;
    for (int n = beg; n < end; ++n) s += us2f(src[(size_t)n * FF + j]);
    out[(size_t)g * FF + j] = s * inv_cnt[g];
}

// ---------------- MFMA bf16 GEMM: out[M x 128] = A @ W (+A2@W2) + epilogue ------
// Block 256 thr, M-tile 64, N=128 (8 n-tiles), K=128. W transposed bf16 [n][k].
// RESM: 0 none, 1 += res_f32[m][col], 2 += A2 LDS tile (bf16)
template<bool DUAL, bool AB16, bool R1, int RESM, int ACT, bool LN, bool OF32, bool OB16>
__global__ __launch_bounds__(256)
void gemm_mfma(const void* __restrict__ A_, const void* __restrict__ A2_,
               const unsigned short* __restrict__ Wt, const unsigned short* __restrict__ W2t,
               const float* __restrict__ bias,
               const float* __restrict__ rvec, const float* __restrict__ rrow,
               const float* __restrict__ res,
               const float* __restrict__ lng, const float* __restrict__ lnb,
               float* __restrict__ outf, unsigned short* __restrict__ outb, int M) {
    constexpr int NA = DUAL ? 2 : 1;
    __shared__ short Al[NA][64 * 136];
    __shared__ short Wl[NA][128 * 40];

    const int t = threadIdx.x;
    const int lane = t & 63, wid = t >> 6;
    const int m0 = blockIdx.x * 64;

    if (AB16) {
        const unsigned short* Ab[2] = {(const unsigned short*)A_, (const unsigned short*)A2_};
        #pragma unroll
        for (int s = 0; s < NA; ++s)
            for (int i = t; i < 1024; i += 256) {
                int row = i >> 4, seg = i & 15;
                int gr = m0 + row; if (gr >= M) gr = M - 1;
                *(uint4*)&Al[s][row * 136 + seg * 8] = *(const uint4*)&Ab[s][(size_t)gr * 128 + seg * 8];
            }
    } else {
        const float* Af[2] = {(const float*)A_, (const float*)A2_};
        #pragma unroll
        for (int s = 0; s < NA; ++s)
            for (int i = t; i < 2048; i += 256) {
                int row = i >> 5, seg = i & 31;
                int gr = m0 + row; if (gr >= M) gr = M - 1;
                float4 v = *(const float4*)&Af[s][(size_t)gr * 128 + seg * 4];
                ushort4 o = {f2b(v.x), f2b(v.y), f2b(v.z), f2b(v.w)};
                *(ushort4*)&Al[s][row * 136 + seg * 4] = o;
            }
    }

    f32x4 acc[8];
    #pragma unroll
    for (int nt = 0; nt < 8; ++nt) acc[nt] = (f32x4){0.f, 0.f, 0.f, 0.f};

    const unsigned short* Wts[2] = {Wt, W2t};
    for (int kc = 0; kc < 4; ++kc) {
        if (kc) __syncthreads();
        #pragma unroll
        for (int s = 0; s < NA; ++s)
            for (int i = t; i < 512; i += 256) {
                int n = i >> 2, seg = i & 3;
                *(uint4*)&Wl[s][n * 40 + seg * 8] =
                    *(const uint4*)&Wts[s][(size_t)n * 128 + kc * 32 + seg * 8];
            }
        __syncthreads();
        const int aoff = (wid * 16 + (lane & 15)) * 136 + kc * 32 + (lane >> 4) * 8;
        short8 a0 = *(const short8*)&Al[0][aoff];
        short8 a1;
        if (DUAL) a1 = *(const short8*)&Al[1][aoff];
        #pragma unroll
        for (int nt = 0; nt < 8; ++nt) {
            const int boff = (nt * 16 + (lane & 15)) * 40 + (lane >> 4) * 8;
            short8 b0 = *(const short8*)&Wl[0][boff];
            acc[nt] = __builtin_amdgcn_mfma_f32_16x16x32_bf16(a0, b0, acc[nt], 0, 0, 0);
            if (DUAL) {
                short8 b1 = *(const short8*)&Wl[1][boff];
                acc[nt] = __builtin_amdgcn_mfma_f32_16x16x32_bf16(a1, b1, acc[nt], 0, 0, 0);
            }
        }
    }

    const int cb = lane & 15, rq = lane >> 4;
    float bs[8], rr[8], lg[8], lb[8];
    #pragma unroll
    for (int nt = 0; nt < 8; ++nt) {
        int col = nt * 16 + cb;
        bs[nt] = bias[col];
        if (R1) rr[nt] = rrow[col];
        if (LN) { lg[nt] = lng[col]; lb[nt] = lnb[col]; }
    }
    #pragma unroll
    for (int reg = 0; reg < 4; ++reg) {
        int r = wid * 16 + rq * 4 + reg;
        int m = m0 + r;
        int mc = m < M ? m : M - 1;
        float v[8];
        #pragma unroll
        for (int nt = 0; nt < 8; ++nt) v[nt] = acc[nt][reg] + bs[nt];
        if (R1) {
            float rv = rvec[mc];
            #pragma unroll
            for (int nt = 0; nt < 8; ++nt) v[nt] += rv * rr[nt];
        }
        if (RESM == 1) {
            #pragma unroll
            for (int nt = 0; nt < 8; ++nt) v[nt] += res[(size_t)mc * 128 + nt * 16 + cb];
        }
        if (RESM == 2) {
            #pragma unroll
            for (int nt = 0; nt < 8; ++nt)
                v[nt] += us2f((unsigned short)Al[NA - 1][r * 136 + nt * 16 + cb]);
        }
        if (ACT == 1) {
            #pragma unroll
            for (int nt = 0; nt < 8; ++nt) v[nt] = v[nt] > 0.f ? v[nt] : expm1f(v[nt]);
        }
        if (LN) {
            float s1 = 0.f, s2 = 0.f;
            #pragma unroll
            for (int nt = 0; nt < 8; ++nt) { s1 += v[nt]; s2 += v[nt] * v[nt]; }
            #pragma unroll
            for (int o = 8; o >= 1; o >>= 1) { s1 += __shfl_xor(s1, o); s2 += __shfl_xor(s2, o); }
            float mu = s1 * (1.f / 128.f);
            float rs = rsqrtf(s2 * (1.f / 128.f) - mu * mu + 1e-5f);
            #pragma unroll
            for (int nt = 0; nt < 8; ++nt) v[nt] = (v[nt] - mu) * rs * lg[nt] + lb[nt];
        }
        if (m < M) {
            #pragma unroll
            for (int nt = 0; nt < 8; ++nt) {
                size_t o = (size_t)m * 128 + nt * 16 + cb;
                if (OF32) outf[o] = v[nt];
                if (OB16) outb[o] = f2b(v[nt]);
            }
        }
    }
}

// ---------------- fused FF block: h = LN(elu(y1@W1+b1)@W2 + b2 + y1) ----------
// 512 threads (8 waves), M-tile 128. ELU intermediate stays in LDS.
__global__ __launch_bounds__(512)
void ff_fused(const unsigned short* __restrict__ y1b,
              const unsigned short* __restrict__ W1t, const unsigned short* __restrict__ W2t,
              const float* __restrict__ bb1, const float* __restrict__ bb2,
              const float* __restrict__ lng, const float* __restrict__ lnb,
              unsigned short* __restrict__ outb, int M) {
    __shared__ short Al[128 * 136];
    __shared__ short Tl[128 * 136];
    __shared__ short Wc[128 * 40];
    const int t = threadIdx.x;
    const int lane = t & 63, wid = t >> 6;
    const int m0 = blockIdx.x * 128;
    const int cb = lane & 15, rq = lane >> 4;
    const int arow = wid * 16 + cb;

    for (int i = t; i < 2048; i += 512) {
        int row = i >> 4, seg = i & 15;
        int gr = m0 + row; if (gr >= M) gr = M - 1;
        *(uint4*)&Al[row * 136 + seg * 8] = *(const uint4*)&y1b[(size_t)gr * 128 + seg * 8];
    }

    f32x4 acc[8];
    #pragma unroll
    for (int nt = 0; nt < 8; ++nt) acc[nt] = (f32x4){0.f, 0.f, 0.f, 0.f};
    for (int kc = 0; kc < 4; ++kc) {
        __syncthreads();
        { int n = t >> 2, seg = t & 3;
          *(uint4*)&Wc[n * 40 + seg * 8] = *(const uint4*)&W1t[(size_t)n * 128 + kc * 32 + seg * 8]; }
        __syncthreads();
        short8 a = *(const short8*)&Al[arow * 136 + kc * 32 + rq * 8];
        #pragma unroll
        for (int nt = 0; nt < 8; ++nt) {
            short8 b = *(const short8*)&Wc[(nt * 16 + cb) * 40 + rq * 8];
            acc[nt] = __builtin_amdgcn_mfma_f32_16x16x32_bf16(a, b, acc[nt], 0, 0, 0);
        }
    }

    float bs1[8];
    #pragma unroll
    for (int nt = 0; nt < 8; ++nt) bs1[nt] = bb1[nt * 16 + cb];
    #pragma unroll
    for (int reg = 0; reg < 4; ++reg) {
        int r = wid * 16 + rq * 4 + reg;
        #pragma unroll
        for (int nt = 0; nt < 8; ++nt) {
            float v = acc[nt][reg] + bs1[nt];
            v = v > 0.f ? v : expm1f(v);
            Tl[r * 136 + nt * 16 + cb] = (short)f2b(v);
        }
    }

    #pragma unroll
    for (int nt = 0; nt < 8; ++nt) acc[nt] = (f32x4){0.f, 0.f, 0.f, 0.f};
    for (int kc = 0; kc < 4; ++kc) {
        __syncthreads();   // also guards Tl writes (kc=0) and Wc reuse
        { int n = t >> 2, seg = t & 3;
          *(uint4*)&Wc[n * 40 + seg * 8] = *(const uint4*)&W2t[(size_t)n * 128 + kc * 32 + seg * 8]; }
        __syncthreads();
        short8 a = *(const short8*)&Tl[arow * 136 + kc * 32 + rq * 8];
        #pragma unroll
        for (int nt = 0; nt < 8; ++nt) {
            short8 b = *(const short8*)&Wc[(nt * 16 + cb) * 40 + rq * 8];
            acc[nt] = __builtin_amdgcn_mfma_f32_16x16x32_bf16(a, b, acc[nt], 0, 0, 0);
        }
    }

    float bs2[8], lg[8], lb[8];
    #pragma unroll
    for (int nt = 0; nt < 8; ++nt) {
        bs2[nt] = bb2[nt * 16 + cb];
        lg[nt] = lng[nt * 16 + cb];
        lb[nt] = lnb[nt * 16 + cb];
    }
    #pragma unroll
    for (int reg = 0; reg < 4; ++reg) {
        int r = wid * 16 + rq * 4 + reg;
        int m = m0 + r;
        float v[8];
        float s1 = 0.f, s2 = 0.f;
        #pragma unroll
        for (int nt = 0; nt < 8; ++nt) {
            v[nt] = acc[nt][reg] + bs2[nt] + us2f((unsigned short)Al[r * 136 + nt * 16 + cb]);
            s1 += v[nt]; s2 += v[nt] * v[nt];
        }
        #pragma unroll
        for (int o = 8; o >= 1; o >>= 1) { s1 += __shfl_xor(s1, o); s2 += __shfl_xor(s2, o); }
        float mu = s1 * (1.f / 128.f);
        float rs = rsqrtf(s2 * (1.f / 128.f) - mu * mu + 1e-5f);
        if (m < M) {
            #pragma unroll
            for (int nt = 0; nt < 8; ++nt)
                outb[(size_t)m * 128 + nt * 16 + cb] = f2b((v[nt] - mu) * rs * lg[nt] + lb[nt]);
        }
    }
}

extern "C" void kernel_launch(void* const* d_in, const int* in_sizes, int n_in,
                              void* d_out, int out_size, void* d_ws, size_t ws_size,
                              hipStream_t stream) {
    const float* x      = (const float*)d_in[0];
    const float* w      = (const float*)d_in[1];
    const int*   ei     = (const int*)d_in[2];
    const int*   batch  = (const int*)d_in[3];
    const float* W_in   = (const float*)d_in[4];
    const float* b_in   = (const float*)d_in[5];
    const float* sage_Wl = (const float*)d_in[6];
    const float* sage_bl = (const float*)d_in[7];
    const float* sage_Wr = (const float*)d_in[8];
    const float* ln1_g  = (const float*)d_in[9];
    const float* ln1_b  = (const float*)d_in[10];
    const float* lin1_W = (const float*)d_in[11];
    const float* lin1_b = (const float*)d_in[12];
    const float* lin2_W = (const float*)d_in[13];
    const float* lin2_b = (const float*)d_in[14];
    const float* ln2_g  = (const float*)d_in[15];
    const float* ln2_b  = (const float*)d_in[16];
    const float* mdf_W  = (const float*)d_in[17];
    const float* mdf_b  = (const float*)d_in[18];
    const float* pln1_g = (const float*)d_in[19];
    const float* pln1_b = (const float*)d_in[20];
    const float* plin1_W = (const float*)d_in[21];
    const float* plin1_b = (const float*)d_in[22];
    const float* plin2_W = (const float*)d_in[23];
    const float* plin2_b = (const float*)d_in[24];
    const float* pln2_g = (const float*)d_in[25];
    const float* pln2_b = (const float*)d_in[26];
    float* out = (float*)d_out;

    const int* e_src = ei;
    const int* e_dst = ei + NE;

    // ---- workspace layout ----
    float* ws = (float*)d_ws;
    size_t off = 0;
    float* gm    = ws + off; off += (size_t)NG * FF;
    float* hh    = ws + off; off += (size_t)NG * FF;
    float* tt    = ws + off; off += (size_t)NG * FF;
    float* inv_deg = ws + off; off += NN;
    float* inv_cnt = ws + off; off += NG;
    unsigned short* us = (unsigned short*)(ws + off);
    size_t uoff = 0;
    unsigned short* hb   = us + uoff; uoff += (size_t)NN * FF;
    unsigned short* aggb = us + uoff; uoff += (size_t)NN * FF;
    unsigned short* y1b  = us + uoff; uoff += (size_t)NN * FF;
    unsigned short* wt   = us + uoff; uoff += (size_t)16 * 16384;
    int* iw = (int*)(us + uoff);
    size_t ioff = 0;
    int* deg_i   = iw + ioff; ioff += NN;
    int* row_off = iw + ioff; ioff += NN + 1;
    int* cursor  = iw + ioff; ioff += NN + 1;
    int* cnt_i   = iw + ioff; ioff += NG;
    int* g_off   = iw + ioff; ioff += NG + 1;
    int* ssrc    = iw + ioff; ioff += NE;

    // ---- weight prep (16 matrices -> transposed bf16) ----
    WTab tab;
    tab.a[0] = W_in;
    for (int l = 0; l < 3; ++l) {
        tab.a[1 + l]  = sage_Wl + (size_t)l * 16384;
        tab.a[4 + l]  = sage_Wr + (size_t)l * 16384;
        tab.a[7 + l]  = lin1_W + (size_t)l * 16384;
        tab.a[10 + l] = lin2_W + (size_t)l * 16384;
    }
    tab.a[13] = mdf_W;      // first 128 rows only (Wa)
    tab.a[14] = plin1_W;
    tab.a[15] = plin2_W;
    prep_weights<<<16 * 64, 256, 0, stream>>>(tab, wt);
    const unsigned short* win_t = wt + 0 * 16384;
    const unsigned short* wa_t  = wt + 13 * 16384;
    const unsigned short* p1_t  = wt + 14 * 16384;
    const unsigned short* p2_t  = wt + 15 * 16384;

    // ---- build CSR + graph offsets ----
    hipMemsetAsync(deg_i, 0, sizeof(int) * NN, stream);
    hipMemsetAsync(cnt_i, 0, sizeof(int) * NG, stream);
    hist_kernel<<<(NE + 255) / 256, 256, 0, stream>>>(e_dst, deg_i, NE);
    hist_kernel<<<(NN + 255) / 256, 256, 0, stream>>>(batch, cnt_i, NN);
    scan_hist<<<1, 1024, 0, stream>>>(deg_i, row_off, cursor, inv_deg, NN);
    scan_hist<<<1, 1024, 0, stream>>>(cnt_i, g_off, (int*)nullptr, inv_cnt, NG);
    scatter_kernel<<<(NE + 255) / 256, 256, 0, stream>>>(e_src, e_dst, cursor, ssrc, NE);

    const int GN = (NN + 63) / 64;     // 1563
    const int GF = (NN + 127) / 128;   // 782
    const int GB = NG / 64;            // 16

    // ---- input linear: hb = bf16(x @ W_in[0:128] + w * W_in[128] + b_in) ----
    gemm_mfma<false, false, true, 0, 0, false, false, true><<<GN, 256, 0, stream>>>(
        x, nullptr, win_t, nullptr, b_in, w, W_in + 128 * 128,
        nullptr, nullptr, nullptr, nullptr, hb, NN);

    // ---- 3 GC blocks ----
    for (int l = 0; l < 3; ++l) {
        const unsigned short* Wl_t = wt + (size_t)(1 + l) * 16384;
        const unsigned short* Wr_t = wt + (size_t)(4 + l) * 16384;
        const unsigned short* W1_t = wt + (size_t)(7 + l) * 16384;
        const unsigned short* W2_t = wt + (size_t)(10 + l) * 16384;
        const float* bl  = sage_bl + (size_t)l * FF;
        const float* g1  = ln1_g + (size_t)l * FF;
        const float* b1  = ln1_b + (size_t)l * FF;
        const float* bb1 = lin1_b + (size_t)l * FF;
        const float* bb2 = lin2_b + (size_t)l * FF;
        const float* g2  = ln2_g + (size_t)l * FF;
        const float* b2  = ln2_b + (size_t)l * FF;

        sage_agg<<<NN / 4, 256, 0, stream>>>(hb, row_off, ssrc, inv_deg, aggb);
        // y1 = LN(agg@Wl + h@Wr + h + bl); residual h taken from A2 LDS tile
        gemm_mfma<true, true, false, 2, 0, true, false, true><<<GN, 256, 0, stream>>>(
            aggb, hb, Wl_t, Wr_t, bl, nullptr, nullptr,
            nullptr, g1, b1, nullptr, y1b, NN);
        // h = LN(elu(y1@W1+bb1)@W2 + bb2 + y1)  (fused, ELU stays in LDS)
        ff_fused<<<GF, 512, 0, stream>>>(y1b, W1_t, W2_t, bb1, bb2, g2, b2, hb, NN);
    }

    // ---- head: pool(h2) == gm @ mdf_W[0:128] + mdf_b  (exact algebra) ----
    pool_mean_b<<<NG, 128, 0, stream>>>(hb, g_off, inv_cnt, gm);
    // hh = LN(gm@Wa + mdf_b)  with pln1 params
    gemm_mfma<false, false, false, 0, 0, true, true, false><<<GB, 256, 0, stream>>>(
        gm, nullptr, wa_t, nullptr, mdf_b, nullptr, nullptr,
        nullptr, pln1_g, pln1_b, hh, nullptr, NG);
    // tt = elu(hh@plin1 + plin1_b)
    gemm_mfma<false, false, false, 0, 1, false, true, false><<<GB, 256, 0, stream>>>(
        hh, nullptr, p1_t, nullptr, plin1_b, nullptr, nullptr,
        nullptr, nullptr, nullptr, tt, nullptr, NG);
    // out = LN(tt@plin2 + plin2_b + hh)  with pln2 params
    gemm_mfma<false, false, false, 1, 0, true, true, false><<<GB, 256, 0, stream>>>(
        tt, nullptr, p2_t, nullptr, plin2_b, nullptr, nullptr,
        hh, pln2_g, pln2_b, out, nullptr, NG);
}